// Round 3
// baseline (150275.208 us; speedup 1.0000x reference)
//
#include <hip/hip_runtime.h>
#include <hip/hip_bf16.h>

// RNN scan: T=1024, B=64, D_IN=1024, H=1024, fp32.
// out = [carry (64*1024)] ++ [outs (1024*64*1024)]
//
// Phase 1: xproj = xs @ Wih + bih  -> written into outs region of d_out.
// Phase 2: persistent scan kernel (256 WGs x 1024 threads) with a
//          low-contention grid barrier per step (flags in d_ws).
//          h_t lives in outs[t] (in place over xproj). Whh column slice
//          staged in LDS once, reused for all 1024 steps.
//          Fallback: if ws_size too small, per-step dispatches (round-2 path).

#define T_STEPS 1024
#define BATCH   64
#define HDIM    1024
#define NWG     256

// ---------- small float4 helpers ----------
__device__ __forceinline__ float4 f4fma(float s, float4 v, float4 a) {
    a.x = fmaf(s, v.x, a.x);
    a.y = fmaf(s, v.y, a.y);
    a.z = fmaf(s, v.z, a.z);
    a.w = fmaf(s, v.w, a.w);
    return a;
}
__device__ __forceinline__ float4 f4add(float4 a, float4 b) {
    return make_float4(a.x + b.x, a.y + b.y, a.z + b.z, a.w + b.w);
}
__device__ __forceinline__ float fast_tanh(float x) {
    float ax = fabsf(x);
    float e  = __expf(2.0f * ax);
    float r  = 1.0f - __fdividef(2.0f, e + 1.0f);
    return copysignf(r, x);
}
__device__ __forceinline__ float4 tanh4(float4 u) {
    return make_float4(fast_tanh(u.x), fast_tanh(u.y), fast_tanh(u.z), fast_tanh(u.w));
}

// ---------- Phase 1: xproj GEMM (fp32, 128x128 tile, 8x8 micro) ----------
__global__ __launch_bounds__(256) void xproj_gemm(
    const float* __restrict__ A,     // xs   [65536,1024]
    const float* __restrict__ W,     // Wih  [1024,1024]
    const float* __restrict__ bias,  // bih  [1024]
    float* __restrict__ C)           // outs [65536,1024]
{
    constexpr int K = 1024, N = 1024;
    __shared__ __align__(16) float As[8][132];
    __shared__ __align__(16) float Ws[8][132];

    const int tid = threadIdx.x;
    const int m0 = blockIdx.y * 128;
    const int n0 = blockIdx.x * 128;
    const int tx = tid & 15;
    const int ty = tid >> 4;

    const int arow = tid >> 1;
    const int kq   = (tid & 1) * 4;
    const int wrow = tid >> 5;
    const int wcol = (tid & 31) * 4;

    float4 c[2][4][2];
#pragma unroll
    for (int rb = 0; rb < 2; ++rb)
#pragma unroll
        for (int i = 0; i < 4; ++i)
#pragma unroll
            for (int cb = 0; cb < 2; ++cb)
                c[rb][i][cb] = make_float4(0.f, 0.f, 0.f, 0.f);

    for (int k0 = 0; k0 < K; k0 += 8) {
        float4 av = *(const float4*)(A + (size_t)(m0 + arow) * K + k0 + kq);
        float4 wv = *(const float4*)(W + (size_t)(k0 + wrow) * N + n0 + wcol);
        __syncthreads();
        As[kq + 0][arow] = av.x;
        As[kq + 1][arow] = av.y;
        As[kq + 2][arow] = av.z;
        As[kq + 3][arow] = av.w;
        *(float4*)&Ws[wrow][wcol] = wv;
        __syncthreads();
#pragma unroll
        for (int kk = 0; kk < 8; ++kk) {
            float4 a0 = *(const float4*)&As[kk][ty * 4];
            float4 a1 = *(const float4*)&As[kk][64 + ty * 4];
            float4 b0 = *(const float4*)&Ws[kk][tx * 4];
            float4 b1 = *(const float4*)&Ws[kk][64 + tx * 4];
            float a0a[4] = {a0.x, a0.y, a0.z, a0.w};
            float a1a[4] = {a1.x, a1.y, a1.z, a1.w};
#pragma unroll
            for (int i = 0; i < 4; ++i) {
                c[0][i][0] = f4fma(a0a[i], b0, c[0][i][0]);
                c[0][i][1] = f4fma(a0a[i], b1, c[0][i][1]);
                c[1][i][0] = f4fma(a1a[i], b0, c[1][i][0]);
                c[1][i][1] = f4fma(a1a[i], b1, c[1][i][1]);
            }
        }
    }

    float4 bv0 = *(const float4*)(bias + n0 + tx * 4);
    float4 bv1 = *(const float4*)(bias + n0 + 64 + tx * 4);
#pragma unroll
    for (int rb = 0; rb < 2; ++rb)
#pragma unroll
        for (int i = 0; i < 4; ++i) {
            int row = m0 + rb * 64 + ty * 4 + i;
            float* cp = C + (size_t)row * N + n0;
            *(float4*)(cp + tx * 4)      = f4add(c[rb][i][0], bv0);
            *(float4*)(cp + 64 + tx * 4) = f4add(c[rb][i][1], bv1);
        }
}

// ---------- grid barrier: per-WG arrival lines + master aggregate ----------
// bar layout (ints): gen @ [0]; flags @ [32 + wg*32] (one 128B line per WG).
// val is monotonically increasing (t+1), so no counter reset races.
__device__ __forceinline__ void gbar(int* __restrict__ bar, int wg, int tid, int val) {
    int* gen   = bar;
    int* flags = bar + 32;
    __threadfence();                 // release: flush h stores to coherence point
    __syncthreads();                 // all waves of this WG done (incl. their fences)
    if (wg != 0) {
        if (tid == 0)
            __hip_atomic_store(&flags[wg * 32], val, __ATOMIC_RELAXED, __HIP_MEMORY_SCOPE_AGENT);
    } else {
        if (tid >= 1 && tid < NWG) {  // 255 parallel pollers, distinct lines
            while (__hip_atomic_load(&flags[tid * 32], __ATOMIC_RELAXED, __HIP_MEMORY_SCOPE_AGENT) < val)
                __builtin_amdgcn_s_sleep(1);
        }
        __syncthreads();
        if (tid == 0)
            __hip_atomic_store(gen, val, __ATOMIC_RELEASE, __HIP_MEMORY_SCOPE_AGENT);
    }
    if (tid == 0) {
        while (__hip_atomic_load(gen, __ATOMIC_RELAXED, __HIP_MEMORY_SCOPE_AGENT) < val)
            __builtin_amdgcn_s_sleep(4);
    }
    __syncthreads();
    __threadfence();                 // acquire: invalidate stale L1/L2 before reading h
}

// ---------- Phase 2: persistent scan ----------
// 256 WGs x 1024 threads. WG owns 4 columns; 16 waves split K (64 each);
// lane = batch row. Whh slice (1024x4 = 16 KB) staged in LDS once.
__global__ __launch_bounds__(1024) void scan_persist(
    const float* __restrict__ init,   // [64,1024]
    const float* __restrict__ Whh,    // [1024,1024]
    const float* __restrict__ bhh,    // [1024]
    float* __restrict__ dout,         // carry @0, outs @65536
    int* __restrict__ bar)            // barrier flags in d_ws
{
    float* carry = dout;
    float* outs  = dout + BATCH * HDIM;

    const int tid = threadIdx.x;
    const int wg  = blockIdx.x;                                // 0..255
    const int b   = tid & 63;                                  // batch row
    const int ks  = __builtin_amdgcn_readfirstlane(tid >> 6);  // wave 0..15
    const int jbase = wg * 4;

    __shared__ __align__(16) float4 Wl[1024];      // Whh[k][jbase..jbase+3]
    __shared__ float parts[4][15][64];             // [j][wave-1][b], conflict-free

    // one-time: stage this WG's Whh column slice (row = tid)
    Wl[tid] = *(const float4*)(Whh + (size_t)tid * HDIM + jbase);
    const float4 bb = *(const float4*)(bhh + jbase);
    __syncthreads();

    for (int t = 0; t < T_STEPS; ++t) {
        const float* hprev = (t == 0) ? init : outs + (size_t)(t - 1) * BATCH * HDIM;
        const float* hrow  = hprev + b * HDIM + ks * 64;

        float4 acc = make_float4(0.f, 0.f, 0.f, 0.f);
        const int kbase = ks * 64;
#pragma unroll 4
        for (int k = 0; k < 64; k += 4) {
            float4 hv = *(const float4*)(hrow + k);
            float4 w0 = Wl[kbase + k + 0];
            float4 w1 = Wl[kbase + k + 1];
            float4 w2 = Wl[kbase + k + 2];
            float4 w3 = Wl[kbase + k + 3];
            acc = f4fma(hv.x, w0, acc);
            acc = f4fma(hv.y, w1, acc);
            acc = f4fma(hv.z, w2, acc);
            acc = f4fma(hv.w, w3, acc);
        }

        if (ks > 0) {
            parts[0][ks - 1][b] = acc.x;
            parts[1][ks - 1][b] = acc.y;
            parts[2][ks - 1][b] = acc.z;
            parts[3][ks - 1][b] = acc.w;
        }
        __syncthreads();
        if (ks == 0) {
            float s0 = acc.x, s1 = acc.y, s2 = acc.z, s3 = acc.w;
#pragma unroll
            for (int i = 0; i < 15; ++i) {
                s0 += parts[0][i][b];
                s1 += parts[1][i][b];
                s2 += parts[2][i][b];
                s3 += parts[3][i][b];
            }
            float* orow = outs + ((size_t)t * BATCH + b) * HDIM + jbase;
            float4 xp = *(const float4*)orow;
            float4 u  = make_float4(xp.x + s0 + bb.x, xp.y + s1 + bb.y,
                                    xp.z + s2 + bb.z, xp.w + s3 + bb.w);
            float4 hv4 = tanh4(u);
            *(float4*)orow = hv4;                       // h_t lives in outs[t]
            if (t == T_STEPS - 1)
                *(float4*)(carry + b * HDIM + jbase) = hv4;
        }
        if (t != T_STEPS - 1)
            gbar(bar, wg, tid, t + 1);
        // last step: kernel-end flush publishes outs[1023] + carry
    }
}

// ---------- Fallback Phase 2: one dispatch per step (round-2 proven path) ----------
__global__ __launch_bounds__(512) void step_kernel(
    const float* __restrict__ Whh,
    const float* __restrict__ bhh,
    const float* __restrict__ h_prev,
    float* __restrict__ out_t,
    float* __restrict__ carry)
{
    const int tid = threadIdx.x;
    const int wg  = blockIdx.x;
    const int b   = tid & 63;
    const int ks  = __builtin_amdgcn_readfirstlane(tid >> 6);  // wave 0..7
    const int jbase = wg * 4;

    __shared__ __align__(16) float part[7][64][4];

    const float* hrow = h_prev + b * HDIM + ks * 128;
    const float* wp   = Whh + (size_t)(ks * 128) * HDIM + jbase;

    float4 acc = make_float4(0.f, 0.f, 0.f, 0.f);
#pragma unroll 4
    for (int k = 0; k < 128; k += 4) {
        float4 hv = *(const float4*)(hrow + k);
        float4 w0 = *(const float4*)(wp + (size_t)(k + 0) * HDIM);
        float4 w1 = *(const float4*)(wp + (size_t)(k + 1) * HDIM);
        float4 w2 = *(const float4*)(wp + (size_t)(k + 2) * HDIM);
        float4 w3 = *(const float4*)(wp + (size_t)(k + 3) * HDIM);
        acc = f4fma(hv.x, w0, acc);
        acc = f4fma(hv.y, w1, acc);
        acc = f4fma(hv.z, w2, acc);
        acc = f4fma(hv.w, w3, acc);
    }

    if (ks > 0) {
        *(float4*)&part[ks - 1][b][0] = acc;
    }
    __syncthreads();
    if (ks == 0) {
#pragma unroll
        for (int i = 0; i < 7; ++i)
            acc = f4add(acc, *(const float4*)&part[i][b][0]);

        float4 bb = *(const float4*)(bhh + jbase);
        float* orow = out_t + b * HDIM + jbase;
        float4 xp = *(const float4*)orow;
        float4 u  = f4add(f4add(xp, acc), bb);
        float4 hv4 = tanh4(u);
        *(float4*)orow = hv4;
        if (carry != nullptr)
            *(float4*)(carry + b * HDIM + jbase) = hv4;
    }
}

extern "C" void kernel_launch(void* const* d_in, const int* in_sizes, int n_in,
                              void* d_out, int out_size, void* d_ws, size_t ws_size,
                              hipStream_t stream) {
    const float* init = (const float*)d_in[0];
    const float* xs   = (const float*)d_in[1];
    const float* Wih  = (const float*)d_in[2];
    const float* bih  = (const float*)d_in[3];
    const float* Whh  = (const float*)d_in[4];
    const float* bhh  = (const float*)d_in[5];
    float* out  = (float*)d_out;
    float* outs = out + BATCH * HDIM;

    // Phase 1: xproj -> outs region of d_out
    xproj_gemm<<<dim3(8, 512), 256, 0, stream>>>(xs, Wih, bih, outs);

    if (ws_size >= 40960) {
        // Phase 2: persistent scan with grid barrier in d_ws
        hipMemsetAsync(d_ws, 0, 36864, stream);   // zero gen + flags (re-poisoned each call)
        scan_persist<<<dim3(NWG), 1024, 0, stream>>>(init, Whh, bhh, out, (int*)d_ws);
    } else {
        // Fallback: per-step dispatches
        for (int t = 0; t < T_STEPS; ++t) {
            const float* hp = (t == 0) ? init : outs + (size_t)(t - 1) * BATCH * HDIM;
            float* ot = outs + (size_t)t * BATCH * HDIM;
            float* cr = (t == T_STEPS - 1) ? out : nullptr;
            step_kernel<<<dim3(256), 512, 0, stream>>>(Whh, bhh, hp, ot, cr);
        }
    }
}